// Round 17
// baseline (138.454 us; speedup 1.0000x reference)
//
#include <hip/hip_runtime.h>
#include <hip/hip_bf16.h>
#include <stdint.h>

#define NROWS 6144
#define MCOLS 6144
#define DDIM  128
#define EPSQ  1e-12f
#define NTC   48          // tiles per side (6144/128)

typedef unsigned long long ull;
typedef __attribute__((ext_vector_type(8))) short short8;
typedef __attribute__((ext_vector_type(4))) float floatx4;

// Order-preserving key: max key == max float value, ties -> smallest index.
__device__ __forceinline__ ull makeKey(float v, int idx) {
    unsigned u = __float_as_uint(v);
    u = (u & 0x80000000u) ? ~u : (u | 0x80000000u);
    return ((ull)u << 32) | (ull)(0xFFFFFFFFu - (unsigned)idx);
}
__device__ __forceinline__ int decodeKeyIdx(ull k) {
    return (int)(0xFFFFFFFFu - (unsigned)(k & 0xFFFFFFFFull));
}
__device__ __forceinline__ unsigned short f2bf(float f) {   // RNE
    unsigned u = __float_as_uint(f);
    u += 0x7fffu + ((u >> 16) & 1);
    return (unsigned short)(u >> 16);
}

// DPP cross-lane within 16-lane rows (VALU pipe, not LDS).
#define DPPF(x, ctrl) __uint_as_float(__builtin_amdgcn_update_dpp( \
    0, (int)__float_as_uint(x), (ctrl), 0xF, 0xF, false))
#define DPPI(x, ctrl) __builtin_amdgcn_update_dpp(0, (x), (ctrl), 0xF, 0xF, false)
#define ROR8 0x128
#define ROR4 0x124
#define ROR2 0x122
#define ROR1 0x121

#define GLOAD16(g, l) \
  __builtin_amdgcn_global_load_lds((const __attribute__((address_space(1))) unsigned int*)(g), \
                                   (__attribute__((address_space(3))) unsigned int*)(l), 16, 0, 0)

// XCD-chunked tile swizzle.
__device__ __forceinline__ void tileCoord(int& rowBase, int& colBase) {
    int id  = blockIdx.x;
    int wid = (id & 7) * (NTC * NTC / 8) + (id >> 3);
    rowBase = (wid / NTC) * 128;
    colBase = (wid % NTC) * 128;
}

// ---------------- K0: convert (vectorized, 8 elems/thread) ------------------
__global__ __launch_bounds__(256) void convert_kernel(
    const float* __restrict__ d1, const float* __restrict__ d2,
    unsigned short* __restrict__ s1, unsigned short* __restrict__ s2,
    float* __restrict__ sq1, float* __restrict__ sq2,
    unsigned* __restrict__ zero_region)
{
    int tid = blockIdx.x * 256 + threadIdx.x;
    if (tid < 36864) zero_region[tid] = 0u;            // rowsum/colsum/rowkey/colkey

    int row = tid >> 4;                                 // 16 threads per row
    int sub = tid & 15;
    if (row >= NROWS + MCOLS) return;
    bool isA = row < NROWS;
    int r = isA ? row : row - NROWS;
    const float* src = (isA ? d1 : d2) + (size_t)r * DDIM + sub * 8;
    unsigned short* dst = (isA ? s1 : s2) + (size_t)r * 256;

    float4 v0 = *(const float4*)(src);
    float4 v1 = *(const float4*)(src + 4);
    float vs[8] = {v0.x, v0.y, v0.z, v0.w, v1.x, v1.y, v1.z, v1.w};

    float s = 0.f;
    #pragma unroll
    for (int j = 0; j < 8; ++j) s += vs[j] * vs[j];
    #pragma unroll
    for (int m = 1; m < 16; m <<= 1) s += __shfl_xor(s, m, 64);
    if (sub == 0) { if (isA) sq1[r] = s; else sq2[r] = s; }

    short8 hi, lo;
    #pragma unroll
    for (int j = 0; j < 8; ++j) {
        unsigned short h = f2bf(vs[j]);
        hi[j] = (short)h;
        lo[j] = (short)f2bf(vs[j] - __uint_as_float((unsigned)h << 16));
    }
    int e  = sub * 8;                                   // 0..120
    int c  = e >> 6;                                    // chunk
    int pe = (e & 63) ^ ((r & 7) << 3);
    *(short8*)(dst + c * 128 + pe)      = hi;
    *(short8*)(dst + c * 128 + 64 + pe) = lo;
}

// Stage one 16KB half-panel (128 rows x 64 elems) of (chunk c, half h) -> buf.
__device__ __forceinline__ void stageBuf(
    const unsigned short* __restrict__ gpanel, unsigned short* buf,
    int c, int h, int t)
{
    #pragma unroll
    for (int it = 0; it < 2; ++it) {
        int li = t * 8 + it * 4096;
        int r  = li >> 6, e = li & 63;
        int gi = r * 256 + c * 128 + h * 64 + e;
        GLOAD16(gpanel + gi, &buf[li]);
    }
}

// One split-product pass over a 64-K chunk: 2 k-steps x 8 MFMA, 12 reads.
// SWAPPED operands: mfma(B,A) => lane holds row=l15, cols=(lane>>4)*4+reg.
__device__ __forceinline__ void computeSplit(
    const unsigned short* Ab_, const unsigned short* Bb_,
    int lane, int wr, int wc, floatx4 acc[4][2])
{
    const int l15 = lane & 15;
    const int q16 = (lane >> 4) * 16;
    const int sw  = (l15 & 7) << 4;
    const char* Ab = (const char*)Ab_;
    const char* Bb = (const char*)Bb_;
    #pragma unroll
    for (int ks = 0; ks < 2; ++ks) {
        const int kk = (ks * 64 + q16) ^ sw;
        short8 af[4], bf[2];
        #pragma unroll
        for (int mi = 0; mi < 4; ++mi)
            af[mi] = *(const short8*)(Ab + (wr * 64 + mi * 16 + l15) * 128 + kk);
        #pragma unroll
        for (int ni = 0; ni < 2; ++ni)
            bf[ni] = *(const short8*)(Bb + (wc * 32 + ni * 16 + l15) * 128 + kk);
        #pragma unroll
        for (int mi = 0; mi < 4; ++mi)
            #pragma unroll
            for (int ni = 0; ni < 2; ++ni)
                acc[mi][ni] = __builtin_amdgcn_mfma_f32_16x16x32_bf16(
                    bf[ni], af[mi], acc[mi][ni], 0, 0, 0);   // SWAPPED
    }
}

// Merged pass: A x (B0 and B1) sharing the A-fragment reads.
__device__ __forceinline__ void computeSplitAB2(
    const unsigned short* Ab_, const unsigned short* B0_, const unsigned short* B1_,
    int lane, int wr, int wc, floatx4 acc[4][2])
{
    const int l15 = lane & 15;
    const int q16 = (lane >> 4) * 16;
    const int sw  = (l15 & 7) << 4;
    const char* Ab = (const char*)Ab_;
    const char* B0 = (const char*)B0_;
    const char* B1 = (const char*)B1_;
    #pragma unroll
    for (int ks = 0; ks < 2; ++ks) {
        const int kk = (ks * 64 + q16) ^ sw;
        short8 af[4], bf0[2], bf1[2];
        #pragma unroll
        for (int mi = 0; mi < 4; ++mi)
            af[mi] = *(const short8*)(Ab + (wr * 64 + mi * 16 + l15) * 128 + kk);
        #pragma unroll
        for (int ni = 0; ni < 2; ++ni) {
            bf0[ni] = *(const short8*)(B0 + (wc * 32 + ni * 16 + l15) * 128 + kk);
            bf1[ni] = *(const short8*)(B1 + (wc * 32 + ni * 16 + l15) * 128 + kk);
        }
        #pragma unroll
        for (int mi = 0; mi < 4; ++mi)
            #pragma unroll
            for (int ni = 0; ni < 2; ++ni)
                acc[mi][ni] = __builtin_amdgcn_mfma_f32_16x16x32_bf16(
                    bf0[ni], af[mi], acc[mi][ni], 0, 0, 0);
        #pragma unroll
        for (int mi = 0; mi < 4; ++mi)
            #pragma unroll
            for (int ni = 0; ni < 2; ++ni)
                acc[mi][ni] = __builtin_amdgcn_mfma_f32_16x16x32_bf16(
                    bf1[ni], af[mi], acc[mi][ni], 0, 0, 0);
    }
}

// ---------------- K1: 3-split GEMM, 3-buffer LDS (51KB) => 3 blocks/CU ------
__global__ __launch_bounds__(512, 6) void gemm_reduce_kernel(
    const unsigned short* __restrict__ s1, const unsigned short* __restrict__ s2,
    const float* __restrict__ invT,
    const float* __restrict__ sq1, const float* __restrict__ sq2,
    float* __restrict__ rowsum, float* __restrict__ colsum,
    ull* __restrict__ rowkey, ull* __restrict__ colkey)
{
    __shared__ unsigned short P[8192], Q[8192], R[8192];   // 48 KB
    __shared__ float lRowS[128], lColS[128];
    __shared__ ull   lRowK[128], lColK[128];               // +3 KB

    const int t = threadIdx.x;
    const int lane = t & 63;
    const int wave = t >> 6;
    const int wr = wave >> 2, wc = wave & 3;
    int rowBase, colBase;
    tileCoord(rowBase, colBase);
    const unsigned short* gA = s1 + (size_t)rowBase * 256;
    const unsigned short* gB = s2 + (size_t)colBase * 256;

    if (t < 128) { lRowS[t] = 0.f; lColS[t] = 0.f; lRowK[t] = 0ull; lColK[t] = 0ull; }

    floatx4 acc[4][2] = {};
    // 3-buffer schedule; stage-only bubbles overlap other blocks' compute.
    stageBuf(gA, P, 0, 0, t); stageBuf(gB, Q, 0, 0, t); stageBuf(gB, R, 0, 1, t);
    __syncthreads();                                        // P=Ah0 Q=Bh0 R=Bl0
    computeSplitAB2(P, Q, R, lane, wr, wc, acc);            // hh0 + hl0
    __syncthreads();
    stageBuf(gA, R, 0, 1, t); stageBuf(gA, P, 1, 0, t);     // R=Al0, P=Ah1
    __syncthreads();                                        // (stage-only)
    computeSplit(R, Q, lane, wr, wc, acc);                  // lh0
    __syncthreads();
    stageBuf(gB, Q, 1, 0, t); stageBuf(gB, R, 1, 1, t);     // Q=Bh1, R=Bl1
    __syncthreads();                                        // (stage-only)
    computeSplitAB2(P, Q, R, lane, wr, wc, acc);            // hh1 + hl1
    __syncthreads();
    stageBuf(gA, R, 1, 1, t);                               // R=Al1
    __syncthreads();                                        // (stage-only)
    computeSplit(R, Q, lane, wr, wc, acc);                  // lh1

    // ---- epilogue ----
    const int l15 = lane & 15;
    const int q   = lane >> 4;
    const float iT = *invT;
    float s1r[4];
    #pragma unroll
    for (int mi = 0; mi < 4; ++mi)
        s1r[mi] = sq1[rowBase + wr * 64 + mi * 16 + l15] + EPSQ;
    const int colLoc0 = wc * 32 + q * 4;
    float4 s2v[2];
    #pragma unroll
    for (int ni = 0; ni < 2; ++ni)
        s2v[ni] = *(const float4*)(sq2 + colBase + colLoc0 + ni * 16);

    float rs[4], rv[4]; int rj[4];
    float cs[2][4], cv[2][4]; int ci[2][4];
    #pragma unroll
    for (int ni = 0; ni < 2; ++ni)
        #pragma unroll
        for (int r = 0; r < 4; ++r) { cs[ni][r] = 0.f; cv[ni][r] = -1e30f; ci[ni][r] = 0; }

    #pragma unroll
    for (int mi = 0; mi < 4; ++mi) {
        const int gi = rowBase + wr * 64 + mi * 16 + l15;
        rs[mi] = 0.f; rv[mi] = -1e30f; rj[mi] = 0;
        #pragma unroll
        for (int ni = 0; ni < 2; ++ni) {
            #pragma unroll
            for (int r = 0; r < 4; ++r) {
                float sv2 = (r == 0) ? s2v[ni].x : (r == 1) ? s2v[ni].y
                          : (r == 2) ? s2v[ni].z : s2v[ni].w;
                float dd = s1r[mi] + sv2 - 2.0f * acc[mi][ni][r];
                float v = -iT * __builtin_amdgcn_sqrtf(fmaxf(dd, EPSQ));
                float e = __expf(v);
                rs[mi] += e;
                if (v > rv[mi]) { rv[mi] = v; rj[mi] = colBase + colLoc0 + ni * 16 + r; }
                cs[ni][r] += e;
                if (v > cv[ni][r]) { cv[ni][r] = v; ci[ni][r] = gi; }   // mi asc -> first occ
            }
        }
    }

    // row reduce (masks 16,32): sum, max, then min-idx of ties
    #pragma unroll
    for (int mi = 0; mi < 4; ++mi) {
        float s = rs[mi];
        s += __shfl_xor(s, 16, 64); s += __shfl_xor(s, 32, 64);
        float v = rv[mi];
        v = fmaxf(v, __shfl_xor(v, 16, 64)); v = fmaxf(v, __shfl_xor(v, 32, 64));
        int cand = (rv[mi] == v) ? rj[mi] : 0x7FFFFFFF;
        cand = min(cand, __shfl_xor(cand, 16, 64));
        cand = min(cand, __shfl_xor(cand, 32, 64));
        if (lane < 16) {
            int idx = wr * 64 + mi * 16 + l15;
            atomicAdd(&lRowS[idx], s);
            atomicMax(&lRowK[idx], makeKey(v, cand));
        }
    }

    // col reduce: DPP rotate-reduce within the 16-lane DPP row
    #pragma unroll
    for (int ni = 0; ni < 2; ++ni)
        #pragma unroll
        for (int r = 0; r < 4; ++r) {
            float s = cs[ni][r];
            s += DPPF(s, ROR8); s += DPPF(s, ROR4); s += DPPF(s, ROR2); s += DPPF(s, ROR1);
            float v = cv[ni][r];
            v = fmaxf(v, DPPF(v, ROR8)); v = fmaxf(v, DPPF(v, ROR4));
            v = fmaxf(v, DPPF(v, ROR2)); v = fmaxf(v, DPPF(v, ROR1));
            int cand = (cv[ni][r] == v) ? ci[ni][r] : 0x7FFFFFFF;
            cand = min(cand, DPPI(cand, ROR8)); cand = min(cand, DPPI(cand, ROR4));
            cand = min(cand, DPPI(cand, ROR2)); cand = min(cand, DPPI(cand, ROR1));
            if (l15 == 0) {
                int idx = colLoc0 + ni * 16 + r;
                atomicAdd(&lColS[idx], s);
                atomicMax(&lColK[idx], makeKey(v, cand));
            }
        }
    __syncthreads();

    if (t < 128) {
        atomicAdd(&rowsum[rowBase + t], lRowS[t]);
        atomicMax(&rowkey[rowBase + t], lRowK[t]);
    } else if (t < 256) {
        int j = t - 128;
        atomicAdd(&colsum[colBase + j], lColS[j]);
        atomicMax(&colkey[colBase + j], lColK[j]);
    }
}

// ---- Kw merged chunk (LDS-staged): 2 split-products (hh + lh) ----
__device__ __forceinline__ void computeChunk2(
    const unsigned short* Ah_, const unsigned short* Al_,
    const unsigned short* Bh_,
    int lane, int wr, int wc, floatx4 acc[4][2])
{
    const int l15 = lane & 15;
    const int q16 = (lane >> 4) * 16;
    const int sw  = (l15 & 7) << 4;
    const char* Ah = (const char*)Ah_;
    const char* Al = (const char*)Al_;
    const char* Bh = (const char*)Bh_;
    #pragma unroll
    for (int ks = 0; ks < 2; ++ks) {
        const int kk = (ks * 64 + q16) ^ sw;
        short8 afh[4], afl[4], bfh[2];
        #pragma unroll
        for (int mi = 0; mi < 4; ++mi) {
            afh[mi] = *(const short8*)(Ah + (wr * 64 + mi * 16 + l15) * 128 + kk);
            afl[mi] = *(const short8*)(Al + (wr * 64 + mi * 16 + l15) * 128 + kk);
        }
        #pragma unroll
        for (int ni = 0; ni < 2; ++ni)
            bfh[ni] = *(const short8*)(Bh + (wc * 32 + ni * 16 + l15) * 128 + kk);
        #pragma unroll
        for (int mi = 0; mi < 4; ++mi)
            #pragma unroll
            for (int ni = 0; ni < 2; ++ni)
                acc[mi][ni] = __builtin_amdgcn_mfma_f32_16x16x32_bf16(
                    bfh[ni], afh[mi], acc[mi][ni], 0, 0, 0);   // hh
        #pragma unroll
        for (int mi = 0; mi < 4; ++mi)
            #pragma unroll
            for (int ni = 0; ni < 2; ++ni)
                acc[mi][ni] = __builtin_amdgcn_mfma_f32_16x16x32_bf16(
                    bfh[ni], afl[mi], acc[mi][ni], 0, 0, 0);   // lh
    }
}

// ---------------- K3: 2-split GEMM (merged) -> LDS transpose -> stores ------
#define VSTRIDE 132
__global__ __launch_bounds__(512, 4) void gemm_write_kernel(
    const unsigned short* __restrict__ s1, const unsigned short* __restrict__ s2,
    const float* __restrict__ invT,
    const float* __restrict__ sq1, const float* __restrict__ sq2,
    const float* __restrict__ rowsum, const float* __restrict__ colsum,
    const ull* __restrict__ rowkey, const ull* __restrict__ colkey,
    float* __restrict__ logp_out, float* __restrict__ p_out,
    float* __restrict__ out_matches, float* __restrict__ out_cyc)
{
    __shared__ char SMEM[128 * VSTRIDE * 4];   // 67584 B; aliases 4x16KB staging
    unsigned short* A0 = (unsigned short*)(SMEM);
    unsigned short* A1 = (unsigned short*)(SMEM + 16384);
    unsigned short* B0 = (unsigned short*)(SMEM + 32768);
    unsigned short* B1 = (unsigned short*)(SMEM + 49152);
    float* V = (float*)SMEM;

    const int t = threadIdx.x;
    const int lane = t & 63;
    const int wave = t >> 6;
    const int wr = wave >> 2, wc = wave & 3;
    int rowBase, colBase;
    tileCoord(rowBase, colBase);
    const unsigned short* gA = s1 + (size_t)rowBase * 256;
    const unsigned short* gB = s2 + (size_t)colBase * 256;

    // ---- folded finalize_small: one block column handles matches/cyc ----
    if (colBase == 0 && t < 128) {
        int i = rowBase + t;
        int mi = decodeKeyIdx(rowkey[i]);
        out_matches[i]         = (float)i;
        out_matches[NROWS + i] = (float)mi;
        out_cyc[i] = (decodeKeyIdx(colkey[mi]) == i) ? 1.0f : 0.0f;
    }

    floatx4 acc[4][2] = {};
    // ---- merged 2-split: Bh of both chunks staged up front ----
    stageBuf(gA, A0, 0, 0, t); stageBuf(gA, A1, 0, 1, t);      // Ah0, Al0
    stageBuf(gB, B0, 0, 0, t); stageBuf(gB, B1, 1, 0, t);      // Bh0, Bh1
    __syncthreads();
    computeChunk2(A0, A1, B0, lane, wr, wc, acc);              // c0
    __syncthreads();
    stageBuf(gA, A0, 1, 0, t); stageBuf(gA, A1, 1, 1, t);      // Ah1, Al1
    __syncthreads();
    computeChunk2(A0, A1, B1, lane, wr, wc, acc);              // c1

    // ---- compute v, park in LDS ----
    const int l15 = lane & 15;
    const int q   = lane >> 4;
    const float iT = *invT;
    float s1r[4];
    #pragma unroll
    for (int mi = 0; mi < 4; ++mi)
        s1r[mi] = sq1[rowBase + wr * 64 + mi * 16 + l15] + EPSQ;
    const int colLoc0 = wc * 32 + q * 4;
    float4 s2v[2];
    #pragma unroll
    for (int ni = 0; ni < 2; ++ni)
        s2v[ni] = *(const float4*)(sq2 + colBase + colLoc0 + ni * 16);

    __syncthreads();                                   // last computeChunk2 reads done
    #pragma unroll
    for (int mi = 0; mi < 4; ++mi) {
        const int lrow = wr * 64 + mi * 16 + l15;
        #pragma unroll
        for (int ni = 0; ni < 2; ++ni) {
            floatx4 vv;
            #pragma unroll
            for (int r = 0; r < 4; ++r) {
                float sv2 = (r == 0) ? s2v[ni].x : (r == 1) ? s2v[ni].y
                          : (r == 2) ? s2v[ni].z : s2v[ni].w;
                float dd = s1r[mi] + sv2 - 2.0f * acc[mi][ni][r];
                vv[r] = -iT * __builtin_amdgcn_sqrtf(fmaxf(dd, EPSQ));
            }
            *(floatx4*)(V + lrow * VSTRIDE + colLoc0 + ni * 16) = vv;
        }
    }
    __syncthreads();

    // ---- re-partitioned stores: each instr covers 4 rows x 256 B ----
    const int rsub = lane >> 4;
    const int csub = (lane & 15) * 4;
    #pragma unroll
    for (int g = 0; g < 4; ++g) {
        const int lrow = wave * 16 + g * 4 + rsub;
        const int grow = rowBase + lrow;
        const float rl = logf(rowsum[grow]);           // inline LSE
        #pragma unroll
        for (int h = 0; h < 2; ++h) {
            const int lcol = h * 64 + csub;
            float4 csum = *(const float4*)(colsum + colBase + lcol);
            float4 cl;
            cl.x = logf(csum.x); cl.y = logf(csum.y);
            cl.z = logf(csum.z); cl.w = logf(csum.w);
            float4 v4 = *(const float4*)(V + lrow * VSTRIDE + lcol);
            floatx4 ov, pv;
            ov[0] = (v4.x - rl) + (v4.x - cl.x); pv[0] = __expf(ov[0]);
            ov[1] = (v4.y - rl) + (v4.y - cl.y); pv[1] = __expf(ov[1]);
            ov[2] = (v4.z - rl) + (v4.z - cl.z); pv[2] = __expf(ov[2]);
            ov[3] = (v4.w - rl) + (v4.w - cl.w); pv[3] = __expf(ov[3]);
            size_t off = (size_t)grow * MCOLS + colBase + lcol;
            __builtin_nontemporal_store(ov, (floatx4*)(logp_out + off));
            __builtin_nontemporal_store(pv, (floatx4*)(p_out + off));
        }
    }
}

extern "C" void kernel_launch(void* const* d_in, const int* in_sizes, int n_in,
                              void* d_out, int out_size, void* d_ws, size_t ws_size,
                              hipStream_t stream) {
    const float* d1   = (const float*)d_in[0];
    const float* d2   = (const float*)d_in[1];
    const float* invT = (const float*)d_in[2];

    float* out     = (float*)d_out;
    float* logp    = out;
    float* pout    = out + (size_t)NROWS * MCOLS;
    float* matches = out + 2ull * NROWS * MCOLS;
    float* cyc     = matches + 2 * NROWS;

    char* ws = (char*)d_ws;
    float* rowsum = (float*)(ws + 0);
    float* colsum = (float*)(ws + 24576);
    ull*   rowkey = (ull*)(ws + 49152);
    ull*   colkey = (ull*)(ws + 98304);
    float* sq1    = (float*)(ws + 147456);
    float* sq2    = (float*)(ws + 172032);
    unsigned short* s1 = (unsigned short*)(ws + 270336);            // [N][256] bf16
    unsigned short* s2 = (unsigned short*)(ws + 270336 + 3145728);  // [M][256] bf16

    convert_kernel<<<(NROWS + MCOLS) * 16 / 256, 256, 0, stream>>>(
        d1, d2, s1, s2, sq1, sq2, (unsigned*)ws);

    gemm_reduce_kernel<<<NTC * NTC, 512, 0, stream>>>(
        s1, s2, invT, sq1, sq2, rowsum, colsum, rowkey, colkey);

    gemm_write_kernel<<<NTC * NTC, 512, 0, stream>>>(
        s1, s2, invT, sq1, sq2, rowsum, colsum, rowkey, colkey,
        logp, pout, matches, cyc);
}

// Round 18
// 129.287 us; speedup vs baseline: 1.0709x; 1.0709x over previous
//
#include <hip/hip_runtime.h>
#include <hip/hip_bf16.h>
#include <stdint.h>

#define NROWS 6144
#define MCOLS 6144
#define DDIM  128
#define EPSQ  1e-12f
#define NTC   48          // tiles per side (6144/128)

typedef unsigned long long ull;
typedef __attribute__((ext_vector_type(8))) short short8;
typedef __attribute__((ext_vector_type(4))) float floatx4;

// Order-preserving key: max key == max float value, ties -> smallest index.
__device__ __forceinline__ ull makeKey(float v, int idx) {
    unsigned u = __float_as_uint(v);
    u = (u & 0x80000000u) ? ~u : (u | 0x80000000u);
    return ((ull)u << 32) | (ull)(0xFFFFFFFFu - (unsigned)idx);
}
__device__ __forceinline__ int decodeKeyIdx(ull k) {
    return (int)(0xFFFFFFFFu - (unsigned)(k & 0xFFFFFFFFull));
}
__device__ __forceinline__ unsigned short f2bf(float f) {   // RNE
    unsigned u = __float_as_uint(f);
    u += 0x7fffu + ((u >> 16) & 1);
    return (unsigned short)(u >> 16);
}

// DPP cross-lane within 16-lane rows (VALU pipe, not LDS).
#define DPPF(x, ctrl) __uint_as_float(__builtin_amdgcn_update_dpp( \
    0, (int)__float_as_uint(x), (ctrl), 0xF, 0xF, false))
#define DPPI(x, ctrl) __builtin_amdgcn_update_dpp(0, (x), (ctrl), 0xF, 0xF, false)
#define ROR8 0x128
#define ROR4 0x124
#define ROR2 0x122
#define ROR1 0x121

#define GLOAD16(g, l) \
  __builtin_amdgcn_global_load_lds((const __attribute__((address_space(1))) unsigned int*)(g), \
                                   (__attribute__((address_space(3))) unsigned int*)(l), 16, 0, 0)

// XCD-chunked tile swizzle.
__device__ __forceinline__ void tileCoord(int& rowBase, int& colBase) {
    int id  = blockIdx.x;
    int wid = (id & 7) * (NTC * NTC / 8) + (id >> 3);
    rowBase = (wid / NTC) * 128;
    colBase = (wid % NTC) * 128;
}

// ---------------- K0: convert (vectorized, 8 elems/thread) ------------------
__global__ __launch_bounds__(256) void convert_kernel(
    const float* __restrict__ d1, const float* __restrict__ d2,
    unsigned short* __restrict__ s1, unsigned short* __restrict__ s2,
    float* __restrict__ sq1, float* __restrict__ sq2,
    unsigned* __restrict__ zero_region)
{
    int tid = blockIdx.x * 256 + threadIdx.x;
    if (tid < 36864) zero_region[tid] = 0u;            // rowsum/colsum/rowkey/colkey

    int row = tid >> 4;                                 // 16 threads per row
    int sub = tid & 15;
    if (row >= NROWS + MCOLS) return;
    bool isA = row < NROWS;
    int r = isA ? row : row - NROWS;
    const float* src = (isA ? d1 : d2) + (size_t)r * DDIM + sub * 8;
    unsigned short* dst = (isA ? s1 : s2) + (size_t)r * 256;

    float4 v0 = *(const float4*)(src);
    float4 v1 = *(const float4*)(src + 4);
    float vs[8] = {v0.x, v0.y, v0.z, v0.w, v1.x, v1.y, v1.z, v1.w};

    float s = 0.f;
    #pragma unroll
    for (int j = 0; j < 8; ++j) s += vs[j] * vs[j];
    #pragma unroll
    for (int m = 1; m < 16; m <<= 1) s += __shfl_xor(s, m, 64);
    if (sub == 0) { if (isA) sq1[r] = s; else sq2[r] = s; }

    short8 hi, lo;
    #pragma unroll
    for (int j = 0; j < 8; ++j) {
        unsigned short h = f2bf(vs[j]);
        hi[j] = (short)h;
        lo[j] = (short)f2bf(vs[j] - __uint_as_float((unsigned)h << 16));
    }
    int e  = sub * 8;                                   // 0..120
    int c  = e >> 6;                                    // chunk
    int pe = (e & 63) ^ ((r & 7) << 3);
    *(short8*)(dst + c * 128 + pe)      = hi;
    *(short8*)(dst + c * 128 + 64 + pe) = lo;
}

// Stage one 16KB half-panel (128 rows x 64 elems) of (chunk c, half h) -> buf.
__device__ __forceinline__ void stageBuf(
    const unsigned short* __restrict__ gpanel, unsigned short* buf,
    int c, int h, int t)
{
    #pragma unroll
    for (int it = 0; it < 2; ++it) {
        int li = t * 8 + it * 4096;
        int r  = li >> 6, e = li & 63;
        int gi = r * 256 + c * 128 + h * 64 + e;
        GLOAD16(gpanel + gi, &buf[li]);
    }
}

// One split-product pass over a 64-K chunk: 2 k-steps x 8 MFMA, 12 reads.
// SWAPPED operands: mfma(B,A) => lane holds row=l15, cols=(lane>>4)*4+reg.
__device__ __forceinline__ void computeSplit(
    const unsigned short* Ab_, const unsigned short* Bb_,
    int lane, int wr, int wc, floatx4 acc[4][2])
{
    const int l15 = lane & 15;
    const int q16 = (lane >> 4) * 16;
    const int sw  = (l15 & 7) << 4;
    const char* Ab = (const char*)Ab_;
    const char* Bb = (const char*)Bb_;
    #pragma unroll
    for (int ks = 0; ks < 2; ++ks) {
        const int kk = (ks * 64 + q16) ^ sw;
        short8 af[4], bf[2];
        #pragma unroll
        for (int mi = 0; mi < 4; ++mi)
            af[mi] = *(const short8*)(Ab + (wr * 64 + mi * 16 + l15) * 128 + kk);
        #pragma unroll
        for (int ni = 0; ni < 2; ++ni)
            bf[ni] = *(const short8*)(Bb + (wc * 32 + ni * 16 + l15) * 128 + kk);
        #pragma unroll
        for (int mi = 0; mi < 4; ++mi)
            #pragma unroll
            for (int ni = 0; ni < 2; ++ni)
                acc[mi][ni] = __builtin_amdgcn_mfma_f32_16x16x32_bf16(
                    bf[ni], af[mi], acc[mi][ni], 0, 0, 0);   // SWAPPED
    }
}

// Merged pass: A x (B0 and B1) sharing the A-fragment reads.
// 2 k-steps x 16 MFMA, 16 reads (vs 24 for two computeSplits).
__device__ __forceinline__ void computeSplitAB2(
    const unsigned short* Ab_, const unsigned short* B0_, const unsigned short* B1_,
    int lane, int wr, int wc, floatx4 acc[4][2])
{
    const int l15 = lane & 15;
    const int q16 = (lane >> 4) * 16;
    const int sw  = (l15 & 7) << 4;
    const char* Ab = (const char*)Ab_;
    const char* B0 = (const char*)B0_;
    const char* B1 = (const char*)B1_;
    #pragma unroll
    for (int ks = 0; ks < 2; ++ks) {
        const int kk = (ks * 64 + q16) ^ sw;
        short8 af[4], bf0[2], bf1[2];
        #pragma unroll
        for (int mi = 0; mi < 4; ++mi)
            af[mi] = *(const short8*)(Ab + (wr * 64 + mi * 16 + l15) * 128 + kk);
        #pragma unroll
        for (int ni = 0; ni < 2; ++ni) {
            bf0[ni] = *(const short8*)(B0 + (wc * 32 + ni * 16 + l15) * 128 + kk);
            bf1[ni] = *(const short8*)(B1 + (wc * 32 + ni * 16 + l15) * 128 + kk);
        }
        #pragma unroll
        for (int mi = 0; mi < 4; ++mi)
            #pragma unroll
            for (int ni = 0; ni < 2; ++ni)
                acc[mi][ni] = __builtin_amdgcn_mfma_f32_16x16x32_bf16(
                    bf0[ni], af[mi], acc[mi][ni], 0, 0, 0);
        #pragma unroll
        for (int mi = 0; mi < 4; ++mi)
            #pragma unroll
            for (int ni = 0; ni < 2; ++ni)
                acc[mi][ni] = __builtin_amdgcn_mfma_f32_16x16x32_bf16(
                    bf1[ni], af[mi], acc[mi][ni], 0, 0, 0);
    }
}

// ---------------- K1: 3-split GEMM (A-merged 5-phase) -> reductions ---------
__global__ __launch_bounds__(512, 4) void gemm_reduce_kernel(
    const unsigned short* __restrict__ s1, const unsigned short* __restrict__ s2,
    const float* __restrict__ invT,
    const float* __restrict__ sq1, const float* __restrict__ sq2,
    float* __restrict__ rowsum, float* __restrict__ colsum,
    ull* __restrict__ rowkey, ull* __restrict__ colkey)
{
    __shared__ unsigned short A0[8192], A1[8192], B0[8192], B1[8192];  // 4x16KB
    __shared__ float lRowS[128], lColS[128];
    __shared__ ull   lRowK[128], lColK[128];

    const int t = threadIdx.x;
    const int lane = t & 63;
    const int wave = t >> 6;
    const int wr = wave >> 2, wc = wave & 3;
    int rowBase, colBase;
    tileCoord(rowBase, colBase);
    const unsigned short* gA = s1 + (size_t)rowBase * 256;
    const unsigned short* gB = s2 + (size_t)colBase * 256;

    if (t < 128) { lRowS[t] = 0.f; lColS[t] = 0.f; lRowK[t] = 0ull; lColK[t] = 0ull; }

    floatx4 acc[4][2] = {};
    // ---- A-merged pipeline: 64 reads, 5 barriers; T5 setprio on MFMA ----
    stageBuf(gA, A0, 0, 0, t); stageBuf(gB, B0, 0, 0, t); stageBuf(gB, B1, 0, 1, t);
    __syncthreads();                                            // Ah0,Bh0,Bl0
    stageBuf(gA, A1, 0, 1, t);                                  // Al0
    __builtin_amdgcn_s_setprio(1);
    computeSplitAB2(A0, B0, B1, lane, wr, wc, acc);             // hh0 + hl0
    __builtin_amdgcn_s_setprio(0);
    __syncthreads();
    stageBuf(gA, A0, 1, 0, t); stageBuf(gB, B1, 1, 0, t);       // Ah1, Bh1
    __builtin_amdgcn_s_setprio(1);
    computeSplit(A1, B0, lane, wr, wc, acc);                    // lh0
    __builtin_amdgcn_s_setprio(0);
    __syncthreads();
    stageBuf(gA, A1, 1, 1, t); stageBuf(gB, B0, 1, 1, t);       // Al1, Bl1
    __builtin_amdgcn_s_setprio(1);
    computeSplit(A0, B1, lane, wr, wc, acc);                    // hh1
    __builtin_amdgcn_s_setprio(0);
    __syncthreads();
    __builtin_amdgcn_s_setprio(1);
    computeSplit(A0, B0, lane, wr, wc, acc);                    // hl1
    computeSplit(A1, B1, lane, wr, wc, acc);                    // lh1
    __builtin_amdgcn_s_setprio(0);

    // ---- epilogue ----
    const int l15 = lane & 15;
    const int q   = lane >> 4;
    const float iT = *invT;
    float s1r[4];
    #pragma unroll
    for (int mi = 0; mi < 4; ++mi)
        s1r[mi] = sq1[rowBase + wr * 64 + mi * 16 + l15] + EPSQ;
    const int colLoc0 = wc * 32 + q * 4;
    float4 s2v[2];
    #pragma unroll
    for (int ni = 0; ni < 2; ++ni)
        s2v[ni] = *(const float4*)(sq2 + colBase + colLoc0 + ni * 16);

    float rs[4], rv[4]; int rj[4];
    float cs[2][4], cv[2][4]; int ci[2][4];
    #pragma unroll
    for (int ni = 0; ni < 2; ++ni)
        #pragma unroll
        for (int r = 0; r < 4; ++r) { cs[ni][r] = 0.f; cv[ni][r] = -1e30f; ci[ni][r] = 0; }

    #pragma unroll
    for (int mi = 0; mi < 4; ++mi) {
        const int gi = rowBase + wr * 64 + mi * 16 + l15;
        rs[mi] = 0.f; rv[mi] = -1e30f; rj[mi] = 0;
        #pragma unroll
        for (int ni = 0; ni < 2; ++ni) {
            #pragma unroll
            for (int r = 0; r < 4; ++r) {
                float sv2 = (r == 0) ? s2v[ni].x : (r == 1) ? s2v[ni].y
                          : (r == 2) ? s2v[ni].z : s2v[ni].w;
                float dd = s1r[mi] + sv2 - 2.0f * acc[mi][ni][r];
                float v = -iT * __builtin_amdgcn_sqrtf(fmaxf(dd, EPSQ));
                float e = __expf(v);
                rs[mi] += e;
                if (v > rv[mi]) { rv[mi] = v; rj[mi] = colBase + colLoc0 + ni * 16 + r; }
                cs[ni][r] += e;
                if (v > cv[ni][r]) { cv[ni][r] = v; ci[ni][r] = gi; }   // mi asc -> first occ
            }
        }
    }

    // row reduce (masks 16,32): sum, max, then min-idx of ties
    #pragma unroll
    for (int mi = 0; mi < 4; ++mi) {
        float s = rs[mi];
        s += __shfl_xor(s, 16, 64); s += __shfl_xor(s, 32, 64);
        float v = rv[mi];
        v = fmaxf(v, __shfl_xor(v, 16, 64)); v = fmaxf(v, __shfl_xor(v, 32, 64));
        int cand = (rv[mi] == v) ? rj[mi] : 0x7FFFFFFF;
        cand = min(cand, __shfl_xor(cand, 16, 64));
        cand = min(cand, __shfl_xor(cand, 32, 64));
        if (lane < 16) {
            int idx = wr * 64 + mi * 16 + l15;
            atomicAdd(&lRowS[idx], s);
            atomicMax(&lRowK[idx], makeKey(v, cand));
        }
    }

    // col reduce: DPP rotate-reduce within the 16-lane DPP row
    #pragma unroll
    for (int ni = 0; ni < 2; ++ni)
        #pragma unroll
        for (int r = 0; r < 4; ++r) {
            float s = cs[ni][r];
            s += DPPF(s, ROR8); s += DPPF(s, ROR4); s += DPPF(s, ROR2); s += DPPF(s, ROR1);
            float v = cv[ni][r];
            v = fmaxf(v, DPPF(v, ROR8)); v = fmaxf(v, DPPF(v, ROR4));
            v = fmaxf(v, DPPF(v, ROR2)); v = fmaxf(v, DPPF(v, ROR1));
            int cand = (cv[ni][r] == v) ? ci[ni][r] : 0x7FFFFFFF;
            cand = min(cand, DPPI(cand, ROR8)); cand = min(cand, DPPI(cand, ROR4));
            cand = min(cand, DPPI(cand, ROR2)); cand = min(cand, DPPI(cand, ROR1));
            if (l15 == 0) {
                int idx = colLoc0 + ni * 16 + r;
                atomicAdd(&lColS[idx], s);
                atomicMax(&lColK[idx], makeKey(v, cand));
            }
        }
    __syncthreads();

    if (t < 128) {
        atomicAdd(&rowsum[rowBase + t], lRowS[t]);
        atomicMax(&rowkey[rowBase + t], lRowK[t]);
    } else if (t < 256) {
        int j = t - 128;
        atomicAdd(&colsum[colBase + j], lColS[j]);
        atomicMax(&colkey[colBase + j], lColK[j]);
    }
}

// ---------------- K3: 2-split GEMM -> LDS transpose -> stores + small fold --
#define VSTRIDE 132
__global__ __launch_bounds__(512, 4) void gemm_write_kernel(
    const unsigned short* __restrict__ s1, const unsigned short* __restrict__ s2,
    const float* __restrict__ invT,
    const float* __restrict__ sq1, const float* __restrict__ sq2,
    const float* __restrict__ rowsum, const float* __restrict__ colsum,
    const ull* __restrict__ rowkey, const ull* __restrict__ colkey,
    float* __restrict__ logp_out, float* __restrict__ p_out,
    float* __restrict__ out_matches, float* __restrict__ out_cyc)
{
    __shared__ char SMEM[128 * VSTRIDE * 4];   // 67584 B; aliases 4x16KB staging
    unsigned short* A0 = (unsigned short*)(SMEM);
    unsigned short* A1 = (unsigned short*)(SMEM + 16384);
    unsigned short* B0 = (unsigned short*)(SMEM + 32768);
    unsigned short* B1 = (unsigned short*)(SMEM + 49152);
    float* V = (float*)SMEM;

    const int t = threadIdx.x;
    const int lane = t & 63;
    const int wave = t >> 6;
    const int wr = wave >> 2, wc = wave & 3;
    int rowBase, colBase;
    tileCoord(rowBase, colBase);
    const unsigned short* gA = s1 + (size_t)rowBase * 256;
    const unsigned short* gB = s2 + (size_t)colBase * 256;

    // ---- folded finalize_small: one block column handles matches/cyc ----
    if (colBase == 0 && t < 128) {
        int i = rowBase + t;
        int mi = decodeKeyIdx(rowkey[i]);
        out_matches[i]         = (float)i;
        out_matches[NROWS + i] = (float)mi;
        out_cyc[i] = (decodeKeyIdx(colkey[mi]) == i) ? 1.0f : 0.0f;
    }

    floatx4 acc[4][2] = {};
    // ---- pipelined 2-split (a*bh = ah*bh + al*bh) x 2 chunks ----
    stageBuf(gA, A0, 0, 0, t); stageBuf(gB, B0, 0, 0, t);      // c0 Ah, Bh
    __syncthreads();
    stageBuf(gA, A1, 0, 1, t); stageBuf(gB, B1, 1, 0, t);      // c0 Al, c1 Bh
    computeSplit(A0, B0, lane, wr, wc, acc);                   // c0 hh
    __syncthreads();
    stageBuf(gA, A0, 1, 0, t);                                 // c1 Ah
    computeSplit(A1, B0, lane, wr, wc, acc);                   // c0 lh
    __syncthreads();
    stageBuf(gA, A1, 1, 1, t);                                 // c1 Al
    computeSplit(A0, B1, lane, wr, wc, acc);                   // c1 hh
    __syncthreads();
    computeSplit(A1, B1, lane, wr, wc, acc);                   // c1 lh

    // ---- compute v, park in LDS ----
    const int l15 = lane & 15;
    const int q   = lane >> 4;
    const float iT = *invT;
    float s1r[4];
    #pragma unroll
    for (int mi = 0; mi < 4; ++mi)
        s1r[mi] = sq1[rowBase + wr * 64 + mi * 16 + l15] + EPSQ;
    const int colLoc0 = wc * 32 + q * 4;
    float4 s2v[2];
    #pragma unroll
    for (int ni = 0; ni < 2; ++ni)
        s2v[ni] = *(const float4*)(sq2 + colBase + colLoc0 + ni * 16);

    __syncthreads();                                   // last computeSplit reads done
    #pragma unroll
    for (int mi = 0; mi < 4; ++mi) {
        const int lrow = wr * 64 + mi * 16 + l15;
        #pragma unroll
        for (int ni = 0; ni < 2; ++ni) {
            floatx4 vv;
            #pragma unroll
            for (int r = 0; r < 4; ++r) {
                float sv2 = (r == 0) ? s2v[ni].x : (r == 1) ? s2v[ni].y
                          : (r == 2) ? s2v[ni].z : s2v[ni].w;
                float dd = s1r[mi] + sv2 - 2.0f * acc[mi][ni][r];
                vv[r] = -iT * __builtin_amdgcn_sqrtf(fmaxf(dd, EPSQ));
            }
            *(floatx4*)(V + lrow * VSTRIDE + colLoc0 + ni * 16) = vv;
        }
    }
    __syncthreads();

    // ---- re-partitioned stores: each instr covers 4 rows x 256 B ----
    const int rsub = lane >> 4;
    const int csub = (lane & 15) * 4;
    #pragma unroll
    for (int g = 0; g < 4; ++g) {
        const int lrow = wave * 16 + g * 4 + rsub;
        const int grow = rowBase + lrow;
        const float rl = logf(rowsum[grow]);           // inline LSE
        #pragma unroll
        for (int h = 0; h < 2; ++h) {
            const int lcol = h * 64 + csub;
            float4 csum = *(const float4*)(colsum + colBase + lcol);
            float4 cl;
            cl.x = logf(csum.x); cl.y = logf(csum.y);
            cl.z = logf(csum.z); cl.w = logf(csum.w);
            float4 v4 = *(const float4*)(V + lrow * VSTRIDE + lcol);
            floatx4 ov, pv;
            ov[0] = (v4.x - rl) + (v4.x - cl.x); pv[0] = __expf(ov[0]);
            ov[1] = (v4.y - rl) + (v4.y - cl.y); pv[1] = __expf(ov[1]);
            ov[2] = (v4.z - rl) + (v4.z - cl.z); pv[2] = __expf(ov[2]);
            ov[3] = (v4.w - rl) + (v4.w - cl.w); pv[3] = __expf(ov[3]);
            size_t off = (size_t)grow * MCOLS + colBase + lcol;
            __builtin_nontemporal_store(ov, (floatx4*)(logp_out + off));
            __builtin_nontemporal_store(pv, (floatx4*)(p_out + off));
        }
    }
}

extern "C" void kernel_launch(void* const* d_in, const int* in_sizes, int n_in,
                              void* d_out, int out_size, void* d_ws, size_t ws_size,
                              hipStream_t stream) {
    const float* d1   = (const float*)d_in[0];
    const float* d2   = (const float*)d_in[1];
    const float* invT = (const float*)d_in[2];

    float* out     = (float*)d_out;
    float* logp    = out;
    float* pout    = out + (size_t)NROWS * MCOLS;
    float* matches = out + 2ull * NROWS * MCOLS;
    float* cyc     = matches + 2 * NROWS;

    char* ws = (char*)d_ws;
    float* rowsum = (float*)(ws + 0);
    float* colsum = (float*)(ws + 24576);
    ull*   rowkey = (ull*)(ws + 49152);
    ull*   colkey = (ull*)(ws + 98304);
    float* sq1    = (float*)(ws + 147456);
    float* sq2    = (float*)(ws + 172032);
    unsigned short* s1 = (unsigned short*)(ws + 270336);            // [N][256] bf16
    unsigned short* s2 = (unsigned short*)(ws + 270336 + 3145728);  // [M][256] bf16

    convert_kernel<<<(NROWS + MCOLS) * 16 / 256, 256, 0, stream>>>(
        d1, d2, s1, s2, sq1, sq2, (unsigned*)ws);

    gemm_reduce_kernel<<<NTC * NTC, 512, 0, stream>>>(
        s1, s2, invT, sq1, sq2, rowsum, colsum, rowkey, colkey);

    gemm_write_kernel<<<NTC * NTC, 512, 0, stream>>>(
        s1, s2, invT, sq1, sq2, rowsum, colsum, rowkey, colkey,
        logp, pout, matches, cyc);
}

// Round 19
// 127.650 us; speedup vs baseline: 1.0846x; 1.0128x over previous
//
#include <hip/hip_runtime.h>
#include <hip/hip_bf16.h>
#include <stdint.h>

#define NROWS 6144
#define MCOLS 6144
#define DDIM  128
#define EPSQ  1e-12f
#define NTC   48          // tiles per side (6144/128)

typedef unsigned long long ull;
typedef __attribute__((ext_vector_type(8))) short short8;
typedef __attribute__((ext_vector_type(4))) float floatx4;

// Order-preserving key: max key == max float value, ties -> smallest index.
__device__ __forceinline__ ull makeKey(float v, int idx) {
    unsigned u = __float_as_uint(v);
    u = (u & 0x80000000u) ? ~u : (u | 0x80000000u);
    return ((ull)u << 32) | (ull)(0xFFFFFFFFu - (unsigned)idx);
}
__device__ __forceinline__ int decodeKeyIdx(ull k) {
    return (int)(0xFFFFFFFFu - (unsigned)(k & 0xFFFFFFFFull));
}
__device__ __forceinline__ unsigned short f2bf(float f) {   // RNE
    unsigned u = __float_as_uint(f);
    u += 0x7fffu + ((u >> 16) & 1);
    return (unsigned short)(u >> 16);
}

// DPP cross-lane within 16-lane rows (VALU pipe, not LDS).
#define DPPF(x, ctrl) __uint_as_float(__builtin_amdgcn_update_dpp( \
    0, (int)__float_as_uint(x), (ctrl), 0xF, 0xF, false))
#define DPPI(x, ctrl) __builtin_amdgcn_update_dpp(0, (x), (ctrl), 0xF, 0xF, false)
#define ROR8 0x128
#define ROR4 0x124
#define ROR2 0x122
#define ROR1 0x121

#define GLOAD16(g, l) \
  __builtin_amdgcn_global_load_lds((const __attribute__((address_space(1))) unsigned int*)(g), \
                                   (__attribute__((address_space(3))) unsigned int*)(l), 16, 0, 0)

// XCD-chunked tile swizzle.
__device__ __forceinline__ void tileCoord(int& rowBase, int& colBase) {
    int id  = blockIdx.x;
    int wid = (id & 7) * (NTC * NTC / 8) + (id >> 3);
    rowBase = (wid / NTC) * 128;
    colBase = (wid % NTC) * 128;
}

// ---------------- K0: convert (vectorized, 8 elems/thread) ------------------
__global__ __launch_bounds__(256) void convert_kernel(
    const float* __restrict__ d1, const float* __restrict__ d2,
    unsigned short* __restrict__ s1, unsigned short* __restrict__ s2,
    float* __restrict__ sq1, float* __restrict__ sq2,
    unsigned* __restrict__ zero_region)
{
    int tid = blockIdx.x * 256 + threadIdx.x;
    if (tid < 36864) zero_region[tid] = 0u;            // rowsum/colsum/rowkey/colkey

    int row = tid >> 4;                                 // 16 threads per row
    int sub = tid & 15;
    if (row >= NROWS + MCOLS) return;
    bool isA = row < NROWS;
    int r = isA ? row : row - NROWS;
    const float* src = (isA ? d1 : d2) + (size_t)r * DDIM + sub * 8;
    unsigned short* dst = (isA ? s1 : s2) + (size_t)r * 256;

    float4 v0 = *(const float4*)(src);
    float4 v1 = *(const float4*)(src + 4);
    float vs[8] = {v0.x, v0.y, v0.z, v0.w, v1.x, v1.y, v1.z, v1.w};

    float s = 0.f;
    #pragma unroll
    for (int j = 0; j < 8; ++j) s += vs[j] * vs[j];
    #pragma unroll
    for (int m = 1; m < 16; m <<= 1) s += __shfl_xor(s, m, 64);
    if (sub == 0) { if (isA) sq1[r] = s; else sq2[r] = s; }

    short8 hi, lo;
    #pragma unroll
    for (int j = 0; j < 8; ++j) {
        unsigned short h = f2bf(vs[j]);
        hi[j] = (short)h;
        lo[j] = (short)f2bf(vs[j] - __uint_as_float((unsigned)h << 16));
    }
    int e  = sub * 8;                                   // 0..120
    int c  = e >> 6;                                    // chunk
    int pe = (e & 63) ^ ((r & 7) << 3);
    *(short8*)(dst + c * 128 + pe)      = hi;
    *(short8*)(dst + c * 128 + 64 + pe) = lo;
}

// Stage one 16KB half-panel (128 rows x 64 elems) of (chunk c, half h) -> buf.
__device__ __forceinline__ void stageBuf(
    const unsigned short* __restrict__ gpanel, unsigned short* buf,
    int c, int h, int t)
{
    #pragma unroll
    for (int it = 0; it < 2; ++it) {
        int li = t * 8 + it * 4096;
        int r  = li >> 6, e = li & 63;
        int gi = r * 256 + c * 128 + h * 64 + e;
        GLOAD16(gpanel + gi, &buf[li]);
    }
}

// One split-product pass over a 64-K chunk: 2 k-steps x 8 MFMA, 12 reads.
// SWAPPED operands: mfma(B,A) => lane holds row=l15, cols=(lane>>4)*4+reg.
__device__ __forceinline__ void computeSplit(
    const unsigned short* Ab_, const unsigned short* Bb_,
    int lane, int wr, int wc, floatx4 acc[4][2])
{
    const int l15 = lane & 15;
    const int q16 = (lane >> 4) * 16;
    const int sw  = (l15 & 7) << 4;
    const char* Ab = (const char*)Ab_;
    const char* Bb = (const char*)Bb_;
    #pragma unroll
    for (int ks = 0; ks < 2; ++ks) {
        const int kk = (ks * 64 + q16) ^ sw;
        short8 af[4], bf[2];
        #pragma unroll
        for (int mi = 0; mi < 4; ++mi)
            af[mi] = *(const short8*)(Ab + (wr * 64 + mi * 16 + l15) * 128 + kk);
        #pragma unroll
        for (int ni = 0; ni < 2; ++ni)
            bf[ni] = *(const short8*)(Bb + (wc * 32 + ni * 16 + l15) * 128 + kk);
        #pragma unroll
        for (int mi = 0; mi < 4; ++mi)
            #pragma unroll
            for (int ni = 0; ni < 2; ++ni)
                acc[mi][ni] = __builtin_amdgcn_mfma_f32_16x16x32_bf16(
                    bf[ni], af[mi], acc[mi][ni], 0, 0, 0);   // SWAPPED
    }
}

// Merged pass: A x (B0 and B1) sharing the A-fragment reads.
// 2 k-steps x 16 MFMA, 16 reads (vs 24 for two computeSplits).
__device__ __forceinline__ void computeSplitAB2(
    const unsigned short* Ab_, const unsigned short* B0_, const unsigned short* B1_,
    int lane, int wr, int wc, floatx4 acc[4][2])
{
    const int l15 = lane & 15;
    const int q16 = (lane >> 4) * 16;
    const int sw  = (l15 & 7) << 4;
    const char* Ab = (const char*)Ab_;
    const char* B0 = (const char*)B0_;
    const char* B1 = (const char*)B1_;
    #pragma unroll
    for (int ks = 0; ks < 2; ++ks) {
        const int kk = (ks * 64 + q16) ^ sw;
        short8 af[4], bf0[2], bf1[2];
        #pragma unroll
        for (int mi = 0; mi < 4; ++mi)
            af[mi] = *(const short8*)(Ab + (wr * 64 + mi * 16 + l15) * 128 + kk);
        #pragma unroll
        for (int ni = 0; ni < 2; ++ni) {
            bf0[ni] = *(const short8*)(B0 + (wc * 32 + ni * 16 + l15) * 128 + kk);
            bf1[ni] = *(const short8*)(B1 + (wc * 32 + ni * 16 + l15) * 128 + kk);
        }
        #pragma unroll
        for (int mi = 0; mi < 4; ++mi)
            #pragma unroll
            for (int ni = 0; ni < 2; ++ni)
                acc[mi][ni] = __builtin_amdgcn_mfma_f32_16x16x32_bf16(
                    bf0[ni], af[mi], acc[mi][ni], 0, 0, 0);
        #pragma unroll
        for (int mi = 0; mi < 4; ++mi)
            #pragma unroll
            for (int ni = 0; ni < 2; ++ni)
                acc[mi][ni] = __builtin_amdgcn_mfma_f32_16x16x32_bf16(
                    bf1[ni], af[mi], acc[mi][ni], 0, 0, 0);
    }
}

// ---------------- K1: 3-split GEMM (A-merged 5-phase) -> reductions ---------
__global__ __launch_bounds__(512, 4) void gemm_reduce_kernel(
    const unsigned short* __restrict__ s1, const unsigned short* __restrict__ s2,
    const float* __restrict__ invT,
    const float* __restrict__ sq1, const float* __restrict__ sq2,
    float* __restrict__ rowsum, float* __restrict__ colsum,
    ull* __restrict__ rowkey, ull* __restrict__ colkey)
{
    __shared__ unsigned short A0[8192], A1[8192], B0[8192], B1[8192];  // 4x16KB
    __shared__ float lRowS[128], lColS[128];
    __shared__ ull   lRowK[128], lColK[128];

    const int t = threadIdx.x;
    const int lane = t & 63;
    const int wave = t >> 6;
    const int wr = wave >> 2, wc = wave & 3;
    int rowBase, colBase;
    tileCoord(rowBase, colBase);
    const unsigned short* gA = s1 + (size_t)rowBase * 256;
    const unsigned short* gB = s2 + (size_t)colBase * 256;

    if (t < 128) { lRowS[t] = 0.f; lColS[t] = 0.f; lRowK[t] = 0ull; lColK[t] = 0ull; }

    floatx4 acc[4][2] = {};
    // ---- A-merged pipeline: 64 reads, 5 barriers ----
    stageBuf(gA, A0, 0, 0, t); stageBuf(gB, B0, 0, 0, t); stageBuf(gB, B1, 0, 1, t);
    __syncthreads();                                            // Ah0,Bh0,Bl0
    stageBuf(gA, A1, 0, 1, t);                                  // Al0
    computeSplitAB2(A0, B0, B1, lane, wr, wc, acc);             // hh0 + hl0
    __syncthreads();
    stageBuf(gA, A0, 1, 0, t); stageBuf(gB, B1, 1, 0, t);       // Ah1, Bh1
    computeSplit(A1, B0, lane, wr, wc, acc);                    // lh0
    __syncthreads();
    stageBuf(gA, A1, 1, 1, t); stageBuf(gB, B0, 1, 1, t);       // Al1, Bl1
    computeSplit(A0, B1, lane, wr, wc, acc);                    // hh1
    __syncthreads();
    computeSplit(A0, B0, lane, wr, wc, acc);                    // hl1
    computeSplit(A1, B1, lane, wr, wc, acc);                    // lh1

    // ---- epilogue ----
    const int l15 = lane & 15;
    const int q   = lane >> 4;
    const float iT = *invT;
    float s1r[4];
    #pragma unroll
    for (int mi = 0; mi < 4; ++mi)
        s1r[mi] = sq1[rowBase + wr * 64 + mi * 16 + l15] + EPSQ;
    const int colLoc0 = wc * 32 + q * 4;
    float4 s2v[2];
    #pragma unroll
    for (int ni = 0; ni < 2; ++ni)
        s2v[ni] = *(const float4*)(sq2 + colBase + colLoc0 + ni * 16);

    float rs[4], rv[4]; int rj[4];
    float cs[2][4], cv[2][4]; int ci[2][4];
    #pragma unroll
    for (int ni = 0; ni < 2; ++ni)
        #pragma unroll
        for (int r = 0; r < 4; ++r) { cs[ni][r] = 0.f; cv[ni][r] = -1e30f; ci[ni][r] = 0; }

    #pragma unroll
    for (int mi = 0; mi < 4; ++mi) {
        const int gi = rowBase + wr * 64 + mi * 16 + l15;
        rs[mi] = 0.f; rv[mi] = -1e30f; rj[mi] = 0;
        #pragma unroll
        for (int ni = 0; ni < 2; ++ni) {
            #pragma unroll
            for (int r = 0; r < 4; ++r) {
                float sv2 = (r == 0) ? s2v[ni].x : (r == 1) ? s2v[ni].y
                          : (r == 2) ? s2v[ni].z : s2v[ni].w;
                float dd = s1r[mi] + sv2 - 2.0f * acc[mi][ni][r];
                float v = -iT * __builtin_amdgcn_sqrtf(fmaxf(dd, EPSQ));
                float e = __expf(v);
                rs[mi] += e;
                if (v > rv[mi]) { rv[mi] = v; rj[mi] = colBase + colLoc0 + ni * 16 + r; }
                cs[ni][r] += e;
                if (v > cv[ni][r]) { cv[ni][r] = v; ci[ni][r] = gi; }   // mi asc -> first occ
            }
        }
    }

    // row reduce (masks 16,32): sum, max, then min-idx of ties
    #pragma unroll
    for (int mi = 0; mi < 4; ++mi) {
        float s = rs[mi];
        s += __shfl_xor(s, 16, 64); s += __shfl_xor(s, 32, 64);
        float v = rv[mi];
        v = fmaxf(v, __shfl_xor(v, 16, 64)); v = fmaxf(v, __shfl_xor(v, 32, 64));
        int cand = (rv[mi] == v) ? rj[mi] : 0x7FFFFFFF;
        cand = min(cand, __shfl_xor(cand, 16, 64));
        cand = min(cand, __shfl_xor(cand, 32, 64));
        if (lane < 16) {
            int idx = wr * 64 + mi * 16 + l15;
            atomicAdd(&lRowS[idx], s);
            atomicMax(&lRowK[idx], makeKey(v, cand));
        }
    }

    // col reduce: DPP rotate-reduce within the 16-lane DPP row
    #pragma unroll
    for (int ni = 0; ni < 2; ++ni)
        #pragma unroll
        for (int r = 0; r < 4; ++r) {
            float s = cs[ni][r];
            s += DPPF(s, ROR8); s += DPPF(s, ROR4); s += DPPF(s, ROR2); s += DPPF(s, ROR1);
            float v = cv[ni][r];
            v = fmaxf(v, DPPF(v, ROR8)); v = fmaxf(v, DPPF(v, ROR4));
            v = fmaxf(v, DPPF(v, ROR2)); v = fmaxf(v, DPPF(v, ROR1));
            int cand = (cv[ni][r] == v) ? ci[ni][r] : 0x7FFFFFFF;
            cand = min(cand, DPPI(cand, ROR8)); cand = min(cand, DPPI(cand, ROR4));
            cand = min(cand, DPPI(cand, ROR2)); cand = min(cand, DPPI(cand, ROR1));
            if (l15 == 0) {
                int idx = colLoc0 + ni * 16 + r;
                atomicAdd(&lColS[idx], s);
                atomicMax(&lColK[idx], makeKey(v, cand));
            }
        }
    __syncthreads();

    if (t < 128) {
        atomicAdd(&rowsum[rowBase + t], lRowS[t]);
        atomicMax(&rowkey[rowBase + t], lRowK[t]);
    } else if (t < 256) {
        int j = t - 128;
        atomicAdd(&colsum[colBase + j], lColS[j]);
        atomicMax(&colkey[colBase + j], lColK[j]);
    }
}

// ---------------- K3: 2-split GEMM -> LDS transpose -> stores + small fold --
#define VSTRIDE 132
__global__ __launch_bounds__(512, 4) void gemm_write_kernel(
    const unsigned short* __restrict__ s1, const unsigned short* __restrict__ s2,
    const float* __restrict__ invT,
    const float* __restrict__ sq1, const float* __restrict__ sq2,
    const float* __restrict__ rowsum, const float* __restrict__ colsum,
    const ull* __restrict__ rowkey, const ull* __restrict__ colkey,
    float* __restrict__ logp_out, float* __restrict__ p_out,
    float* __restrict__ out_matches, float* __restrict__ out_cyc)
{
    __shared__ char SMEM[128 * VSTRIDE * 4];   // 67584 B; aliases 4x16KB staging
    unsigned short* A0 = (unsigned short*)(SMEM);
    unsigned short* A1 = (unsigned short*)(SMEM + 16384);
    unsigned short* B0 = (unsigned short*)(SMEM + 32768);
    unsigned short* B1 = (unsigned short*)(SMEM + 49152);
    float* V = (float*)SMEM;

    const int t = threadIdx.x;
    const int lane = t & 63;
    const int wave = t >> 6;
    const int wr = wave >> 2, wc = wave & 3;
    int rowBase, colBase;
    tileCoord(rowBase, colBase);
    const unsigned short* gA = s1 + (size_t)rowBase * 256;
    const unsigned short* gB = s2 + (size_t)colBase * 256;

    // ---- folded finalize_small: one block column handles matches/cyc ----
    if (colBase == 0 && t < 128) {
        int i = rowBase + t;
        int mi = decodeKeyIdx(rowkey[i]);
        out_matches[i]         = (float)i;
        out_matches[NROWS + i] = (float)mi;
        out_cyc[i] = (decodeKeyIdx(colkey[mi]) == i) ? 1.0f : 0.0f;
    }

    floatx4 acc[4][2] = {};
    // ---- pipelined 2-split (a*bh = ah*bh + al*bh) x 2 chunks ----
    stageBuf(gA, A0, 0, 0, t); stageBuf(gB, B0, 0, 0, t);      // c0 Ah, Bh
    __syncthreads();
    stageBuf(gA, A1, 0, 1, t); stageBuf(gB, B1, 1, 0, t);      // c0 Al, c1 Bh
    computeSplit(A0, B0, lane, wr, wc, acc);                   // c0 hh
    __syncthreads();
    stageBuf(gA, A0, 1, 0, t);                                 // c1 Ah
    computeSplit(A1, B0, lane, wr, wc, acc);                   // c0 lh
    __syncthreads();
    stageBuf(gA, A1, 1, 1, t);                                 // c1 Al
    computeSplit(A0, B1, lane, wr, wc, acc);                   // c1 hh
    __syncthreads();
    computeSplit(A1, B1, lane, wr, wc, acc);                   // c1 lh

    // ---- compute v, park in LDS ----
    const int l15 = lane & 15;
    const int q   = lane >> 4;
    const float iT = *invT;
    float s1r[4];
    #pragma unroll
    for (int mi = 0; mi < 4; ++mi)
        s1r[mi] = sq1[rowBase + wr * 64 + mi * 16 + l15] + EPSQ;
    const int colLoc0 = wc * 32 + q * 4;
    float4 s2v[2];
    #pragma unroll
    for (int ni = 0; ni < 2; ++ni)
        s2v[ni] = *(const float4*)(sq2 + colBase + colLoc0 + ni * 16);

    __syncthreads();                                   // last computeSplit reads done
    #pragma unroll
    for (int mi = 0; mi < 4; ++mi) {
        const int lrow = wr * 64 + mi * 16 + l15;
        #pragma unroll
        for (int ni = 0; ni < 2; ++ni) {
            floatx4 vv;
            #pragma unroll
            for (int r = 0; r < 4; ++r) {
                float sv2 = (r == 0) ? s2v[ni].x : (r == 1) ? s2v[ni].y
                          : (r == 2) ? s2v[ni].z : s2v[ni].w;
                float dd = s1r[mi] + sv2 - 2.0f * acc[mi][ni][r];
                vv[r] = -iT * __builtin_amdgcn_sqrtf(fmaxf(dd, EPSQ));
            }
            *(floatx4*)(V + lrow * VSTRIDE + colLoc0 + ni * 16) = vv;
        }
    }
    __syncthreads();

    // ---- re-partitioned stores: each instr covers 4 rows x 256 B ----
    const int rsub = lane >> 4;
    const int csub = (lane & 15) * 4;
    #pragma unroll
    for (int g = 0; g < 4; ++g) {
        const int lrow = wave * 16 + g * 4 + rsub;
        const int grow = rowBase + lrow;
        const float rl = logf(rowsum[grow]);           // inline LSE
        #pragma unroll
        for (int h = 0; h < 2; ++h) {
            const int lcol = h * 64 + csub;
            float4 csum = *(const float4*)(colsum + colBase + lcol);
            float4 cl;
            cl.x = logf(csum.x); cl.y = logf(csum.y);
            cl.z = logf(csum.z); cl.w = logf(csum.w);
            float4 v4 = *(const float4*)(V + lrow * VSTRIDE + lcol);
            floatx4 ov, pv;
            ov[0] = (v4.x - rl) + (v4.x - cl.x); pv[0] = __expf(ov[0]);
            ov[1] = (v4.y - rl) + (v4.y - cl.y); pv[1] = __expf(ov[1]);
            ov[2] = (v4.z - rl) + (v4.z - cl.z); pv[2] = __expf(ov[2]);
            ov[3] = (v4.w - rl) + (v4.w - cl.w); pv[3] = __expf(ov[3]);
            size_t off = (size_t)grow * MCOLS + colBase + lcol;
            __builtin_nontemporal_store(ov, (floatx4*)(logp_out + off));
            __builtin_nontemporal_store(pv, (floatx4*)(p_out + off));
        }
    }
}

extern "C" void kernel_launch(void* const* d_in, const int* in_sizes, int n_in,
                              void* d_out, int out_size, void* d_ws, size_t ws_size,
                              hipStream_t stream) {
    const float* d1   = (const float*)d_in[0];
    const float* d2   = (const float*)d_in[1];
    const float* invT = (const float*)d_in[2];

    float* out     = (float*)d_out;
    float* logp    = out;
    float* pout    = out + (size_t)NROWS * MCOLS;
    float* matches = out + 2ull * NROWS * MCOLS;
    float* cyc     = matches + 2 * NROWS;

    char* ws = (char*)d_ws;
    float* rowsum = (float*)(ws + 0);
    float* colsum = (float*)(ws + 24576);
    ull*   rowkey = (ull*)(ws + 49152);
    ull*   colkey = (ull*)(ws + 98304);
    float* sq1    = (float*)(ws + 147456);
    float* sq2    = (float*)(ws + 172032);
    unsigned short* s1 = (unsigned short*)(ws + 270336);            // [N][256] bf16
    unsigned short* s2 = (unsigned short*)(ws + 270336 + 3145728);  // [M][256] bf16

    convert_kernel<<<(NROWS + MCOLS) * 16 / 256, 256, 0, stream>>>(
        d1, d2, s1, s2, sq1, sq2, (unsigned*)ws);

    gemm_reduce_kernel<<<NTC * NTC, 512, 0, stream>>>(
        s1, s2, invT, sq1, sq2, rowsum, colsum, rowkey, colkey);

    gemm_write_kernel<<<NTC * NTC, 512, 0, stream>>>(
        s1, s2, invT, sq1, sq2, rowsum, colsum, rowkey, colkey,
        logp, pout, matches, cyc);
}